// Round 3
// baseline (1438.999 us; speedup 1.0000x reference)
//
#include <hip/hip_runtime.h>

// GRU: B=256, T=2048, I=2, H=128. One workgroup (512 thr = 8 waves) per batch.
// Thread (q=tid&3, j=tid>>2) owns 32-col slice q of gate rows {j, 128+j, 256+j}:
// 3x8 float4 weights pinned in VGPRs (amdgpu_waves_per_eu(2,2) + asm pins to
// defeat rematerialization — R2's VGPR_Count=68 showed the backend re-loading
// weights from global every step). h double-buffered in LDS, one barrier/step.
// Partial dots combined with intra-quad __shfl_xor(1,2) (DPP, ~free).

#define BB 256
#define TT 2048
#define HH 128
#define NT 512
#define HWORDS 160   // h layout: block q at word 40*q (pad keeps q-banks disjoint)

#define PIN(v) asm volatile("" : "+v"(v))
#define PIN4(f4) do { PIN((f4).x); PIN((f4).y); PIN((f4).z); PIN((f4).w); } while (0)

__device__ __forceinline__ float fast_sigmoid(float v) {
    return 1.0f / (1.0f + __expf(-v));
}
__device__ __forceinline__ float fast_tanh(float v) {
    v = fminf(fmaxf(v, -30.0f), 30.0f);
    float e = __expf(2.0f * v);
    return (e - 1.0f) / (e + 1.0f);
}

__global__ __launch_bounds__(NT)
__attribute__((amdgpu_waves_per_eu(2, 2)))
void gru_seq_kernel(
    const float* __restrict__ x,        // [B, T, 2]
    const int*   __restrict__ lengths,  // [B]
    const float* __restrict__ W_ih,     // [384, 2]
    const float* __restrict__ W_hh,     // [384, 128]
    const float* __restrict__ b_ih,     // [384]
    const float* __restrict__ b_hh,     // [384]
    const float* __restrict__ head_w,   // [128]
    const float* __restrict__ head_b,   // [1]
    float* __restrict__ out)            // [B]
{
    __shared__ __align__(16) float x_lds[TT * 2];        // 16 KB
    __shared__ __align__(16) float h_lds[2][HWORDS];     // 1.25 KB
    __shared__ float red[8];

    const int tid = threadIdx.x;
    const int q = tid & 3;          // 32-col slice
    const int j = tid >> 2;         // hidden index 0..127
    const int b = blockIdx.x;
    const int len = lengths[b];

    // --- weights for this thread's 3 row-slices (96 VGPRs) ---
    float4 wr[8], wz[8], wn[8];
    {
        const float4* Wr = (const float4*)(W_hh + (size_t)j * HH + q * 32);
        const float4* Wz = (const float4*)(W_hh + (size_t)(HH + j) * HH + q * 32);
        const float4* Wn = (const float4*)(W_hh + (size_t)(2 * HH + j) * HH + q * 32);
        #pragma unroll
        for (int i = 0; i < 8; ++i) { wr[i] = Wr[i]; wz[i] = Wz[i]; wn[i] = Wn[i]; }
    }
    // pin weights: asm-defined values cannot be rematerialized from memory
    #pragma unroll
    for (int i = 0; i < 8; ++i) { PIN4(wr[i]); PIN4(wz[i]); PIN4(wn[i]); }

    // per-j scalar params (only q==0 lane uses them)
    float wir0 = 0.f, wir1 = 0.f, bir = 0.f;
    float wiz0 = 0.f, wiz1 = 0.f, biz = 0.f;
    float win0 = 0.f, win1 = 0.f, bin = 0.f;
    float bhr = 0.f, bhz = 0.f, bhn = 0.f, hw = 0.f;
    if (q == 0) {
        wir0 = W_ih[j * 2];            wir1 = W_ih[j * 2 + 1];            bir = b_ih[j];
        wiz0 = W_ih[(HH + j) * 2];     wiz1 = W_ih[(HH + j) * 2 + 1];     biz = b_ih[HH + j];
        win0 = W_ih[(2 * HH + j) * 2]; win1 = W_ih[(2 * HH + j) * 2 + 1]; bin = b_ih[2 * HH + j];
        bhr = b_hh[j]; bhz = b_hh[HH + j]; bhn = b_hh[2 * HH + j];
        hw = head_w[j];
    }

    // --- stage x[b] into LDS (float4, coalesced) ---
    {
        const float4* xb4 = (const float4*)(x + (size_t)b * TT * 2);
        float4* xl4 = (float4*)x_lds;
        #pragma unroll
        for (int i = tid; i < TT * 2 / 4; i += NT) xl4[i] = xb4[i];
    }
    // zero both h buffers
    for (int i = tid; i < 2 * HWORDS; i += NT) ((float*)h_lds)[i] = 0.f;

    __syncthreads();

    float h_reg = 0.0f;   // h[j] held by q==0 lanes
    int buf = 0;
    const float2* x2 = (const float2*)x_lds;

    for (int t = 0; t < len; ++t) {
        const float2 xt = x2[t];
        const float x0 = xt.x, x1 = xt.y;

        // read this thread's h slice once (same addr across quad → broadcast)
        const float4* hb = (const float4*)&h_lds[buf][40 * q];
        float4 hv[8];
        #pragma unroll
        for (int i = 0; i < 8; ++i) hv[i] = hb[i];

        // split accumulators: dep chain 16 FMAs instead of 32
        float ar0 = 0.f, ar1 = 0.f, az0 = 0.f, az1 = 0.f, an0 = 0.f, an1 = 0.f;
        #pragma unroll
        for (int i = 0; i < 4; ++i) {
            const float4 ha = hv[2 * i], hc = hv[2 * i + 1];
            ar0 = fmaf(wr[2*i].x, ha.x, fmaf(wr[2*i].y, ha.y, fmaf(wr[2*i].z, ha.z, fmaf(wr[2*i].w, ha.w, ar0))));
            ar1 = fmaf(wr[2*i+1].x, hc.x, fmaf(wr[2*i+1].y, hc.y, fmaf(wr[2*i+1].z, hc.z, fmaf(wr[2*i+1].w, hc.w, ar1))));
            az0 = fmaf(wz[2*i].x, ha.x, fmaf(wz[2*i].y, ha.y, fmaf(wz[2*i].z, ha.z, fmaf(wz[2*i].w, ha.w, az0))));
            az1 = fmaf(wz[2*i+1].x, hc.x, fmaf(wz[2*i+1].y, hc.y, fmaf(wz[2*i+1].z, hc.z, fmaf(wz[2*i+1].w, hc.w, az1))));
            an0 = fmaf(wn[2*i].x, ha.x, fmaf(wn[2*i].y, ha.y, fmaf(wn[2*i].z, ha.z, fmaf(wn[2*i].w, ha.w, an0))));
            an1 = fmaf(wn[2*i+1].x, hc.x, fmaf(wn[2*i+1].y, hc.y, fmaf(wn[2*i+1].z, hc.z, fmaf(wn[2*i+1].w, hc.w, an1))));
        }
        float ar = ar0 + ar1, az = az0 + az1, an = an0 + an1;

        // combine q-slices (intra-quad DPP shuffles)
        ar += __shfl_xor(ar, 1); ar += __shfl_xor(ar, 2);
        az += __shfl_xor(az, 1); az += __shfl_xor(az, 2);
        an += __shfl_xor(an, 1); an += __shfl_xor(an, 2);

        if (q == 0) {
            const float r  = fast_sigmoid(fmaf(wir0, x0, fmaf(wir1, x1, bir)) + ar + bhr);
            const float z  = fast_sigmoid(fmaf(wiz0, x0, fmaf(wiz1, x1, biz)) + az + bhz);
            const float hn = an + bhn;
            const float xn = fmaf(win0, x0, fmaf(win1, x1, bin));
            const float n  = fast_tanh(fmaf(r, hn, xn));
            h_reg = n + z * (h_reg - n);
            h_lds[buf ^ 1][40 * (j >> 5) + (j & 31)] = h_reg;
        }
        __syncthreads();
        buf ^= 1;
    }

    // --- head: out[b] = dot(h, head_w) + head_b ---
    float p = (q == 0) ? h_reg * hw : 0.0f;
    #pragma unroll
    for (int off = 32; off > 0; off >>= 1) p += __shfl_xor(p, off);
    const int wid = tid >> 6;
    if ((tid & 63) == 0) red[wid] = p;
    __syncthreads();
    if (tid == 0) {
        float s = red[0];
        #pragma unroll
        for (int i = 1; i < 8; ++i) s += red[i];
        out[b] = s + head_b[0];
    }
}

extern "C" void kernel_launch(void* const* d_in, const int* in_sizes, int n_in,
                              void* d_out, int out_size, void* d_ws, size_t ws_size,
                              hipStream_t stream) {
    const float* x      = (const float*)d_in[0];
    const int*   len    = (const int*)  d_in[1];
    const float* W_ih   = (const float*)d_in[2];
    const float* W_hh   = (const float*)d_in[3];
    const float* b_ih   = (const float*)d_in[4];
    const float* b_hh   = (const float*)d_in[5];
    const float* head_w = (const float*)d_in[6];
    const float* head_b = (const float*)d_in[7];
    float* out = (float*)d_out;

    gru_seq_kernel<<<BB, NT, 0, stream>>>(x, len, W_ih, W_hh, b_ih, b_hh,
                                          head_w, head_b, out);
}